// Round 16
// baseline (922.525 us; speedup 1.0000x reference)
//
#include <hip/hip_runtime.h>

typedef unsigned short u16;
typedef unsigned int   u32;
typedef __attribute__((ext_vector_type(8))) __bf16 bfv8;
typedef __attribute__((ext_vector_type(4))) float  f32x4;
typedef __attribute__((ext_vector_type(4))) u32    u32x4;

// ---------- helpers ----------
__device__ __forceinline__ u16 f2bf(float f){
  __bf16 b = (__bf16)f;                       // native v_cvt (RNE)
  return __builtin_bit_cast(u16, b);
}
__device__ __forceinline__ float bf2f(u16 b){
  return __builtin_bit_cast(float, ((u32)b) << 16);
}
__device__ __forceinline__ u32 pk2(float a, float b){
  return (u32)f2bf(a) | ((u32)f2bf(b) << 16);
}
__device__ __forceinline__ float wsum(float v){
  #pragma unroll
  for (int m = 32; m > 0; m >>= 1) v += __shfl_xor(v, m, 64);
  return v;
}
__device__ __forceinline__ void gload16(const void* g, void* l){
  __builtin_amdgcn_global_load_lds((const __attribute__((address_space(1))) void*)g,
                                   (__attribute__((address_space(3))) void*)l, 16, 0, 0);
}

// ---------- weight f32 -> bf16 conversion (nontemporal, 32B/thread/iter) ----------
struct CBatch { const float* s[12]; long long p4[13]; u16* dst; };
__global__ __launch_bounds__(256) void flm_conv(CBatch cb)
{
  const int seg = blockIdx.y;
  const long long base = cb.p4[seg];                 // float4 units
  const long long n8 = (cb.p4[seg + 1] - base) >> 1; // 8-float units
  const f32x4* __restrict__ src = (const f32x4*)cb.s[seg];
  u32x4* __restrict__ dst = (u32x4*)cb.dst + (base >> 1);
  for (long long i = (long long)blockIdx.x * 256 + threadIdx.x; i < n8;
       i += (long long)gridDim.x * 256){
    f32x4 v0 = __builtin_nontemporal_load(src + 2*i);
    f32x4 v1 = __builtin_nontemporal_load(src + 2*i + 1);
    u32x4 p;
    p.x = pk2(v0.x, v0.y); p.y = pk2(v0.z, v0.w);
    p.z = pk2(v1.x, v1.y); p.w = pk2(v1.z, v1.w);
    __builtin_nontemporal_store(p, dst + i);
  }
}

// ---------- multi-GEMM (512 thr, 8 waves, 128x128 tile, acc 4x2/wave) ----------
// BW=true: bf16 A and W via global_load_lds + XOR swizzle (rule #21).
// epi: 0 = f32 store, 1 = bf16 store, 2 = bf16 TRANSPOSED store (C^T), 5 = f32 atomicAdd
struct GDesc {
  const u16* A; const float* Bw; float* Cf; u16* Cb;
  int lda, ldb, ldc, kbeg, kend, blk0, epi, pad;
};
struct GBatch { GDesc d[6]; int ng, total; };

template<bool BW>
__global__ __launch_bounds__(512) void flm_mgemm(GBatch gb)
{
  constexpr int LDK = BW ? 64 : 72;
  __shared__ u16 sA[128][LDK];
  __shared__ u16 sB[128][LDK];
  const int tid = threadIdx.x, lane = tid & 63, w = tid >> 6;

  const int T = gb.total, bid = blockIdx.x;
  const int q8 = T >> 3, r8 = T & 7, xc = bid & 7, of = bid >> 3;
  const int lin = (xc < r8 ? xc * (q8 + 1) : r8 * (q8 + 1) + (xc - r8) * q8) + of;
  int di = 0;
  #pragma unroll
  for (int i = 1; i < 6; i++) if (i < gb.ng && lin >= gb.d[i].blk0) di = i;
  const GDesc g = gb.d[di];
  const int local = lin - g.blk0;
  const int row0 = (local & 7) * 128;
  const int col0 = (local >> 3) * 128;
  const int wr = (w >> 2) * 64, wc = (w & 3) * 32;

  f32x4 acc[4][2];
  #pragma unroll
  for (int m = 0; m < 4; m++)
    #pragma unroll
    for (int n = 0; n < 2; n++)
      acc[m][n] = (f32x4){0.f, 0.f, 0.f, 0.f};

  const int csw = ((lane & 7) ^ (lane >> 3)) * 8;   // inverse-swizzled src col (elems)
  const u16* B16 = (const u16*)g.Bw;

  for (int k0 = g.kbeg; k0 < g.kend; k0 += 64){
    if constexpr (BW){
      const u16* a0 = g.A + (size_t)(row0 + w*16 + (lane>>3)) * g.lda + k0 + csw;
      const u16* b0 = B16 + (size_t)(col0 + w*16 + (lane>>3)) * g.ldb + k0 + csw;
      gload16(a0,                     &sA[w*16    ][0]);
      gload16(a0 + (size_t)8*g.lda,   &sA[w*16 + 8][0]);
      gload16(b0,                     &sB[w*16    ][0]);
      gload16(b0 + (size_t)8*g.ldb,   &sB[w*16 + 8][0]);
    } else {
      #pragma unroll
      for (int i = 0; i < 2; i++){
        int idx = tid + i * 512;
        int r = idx >> 3, c = (idx & 7) * 8;
        *(uint4*)&sA[r][c] = *(const uint4*)(g.A + (size_t)(row0 + r) * g.lda + k0 + c);
      }
      #pragma unroll
      for (int i = 0; i < 4; i++){
        int idx = tid + i * 512;
        int r = idx >> 4, c = (idx & 15) * 4;
        float4 v = *(const float4*)(g.Bw + (size_t)(col0 + r) * g.ldb + k0 + c);
        uint2 p; p.x = pk2(v.x, v.y); p.y = pk2(v.z, v.w);
        *(uint2*)&sB[r][c] = p;
      }
    }
    __syncthreads();
    #pragma unroll
    for (int kk = 0; kk < 2; kk++){
      bfv8 af[4], bfr[2];
      #pragma unroll
      for (int m = 0; m < 4; m++){
        int row = wr + m*16 + (lane & 15);
        if constexpr (BW){
          int slot = (kk*4 + (lane >> 4)) ^ (row & 7);
          af[m] = *(const bfv8*)((const char*)sA + row*128 + slot*16);
        } else {
          af[m] = *(const bfv8*)&sA[row][kk*32 + (lane >> 4) * 8];
        }
      }
      #pragma unroll
      for (int n = 0; n < 2; n++){
        int row = wc + n*16 + (lane & 15);
        if constexpr (BW){
          int slot = (kk*4 + (lane >> 4)) ^ (row & 7);
          bfr[n] = *(const bfv8*)((const char*)sB + row*128 + slot*16);
        } else {
          bfr[n] = *(const bfv8*)&sB[row][kk*32 + (lane >> 4) * 8];
        }
      }
      #pragma unroll
      for (int m = 0; m < 4; m++)
        #pragma unroll
        for (int n = 0; n < 2; n++)
          acc[m][n] = __builtin_amdgcn_mfma_f32_16x16x32_bf16(af[m], bfr[n], acc[m][n], 0, 0, 0);
    }
    __syncthreads();
  }

  #pragma unroll
  for (int m = 0; m < 4; m++){
    int rbase = row0 + wr + m*16 + (lane >> 4) * 4;
    #pragma unroll
    for (int n = 0; n < 2; n++){
      int col = col0 + wc + n*16 + (lane & 15);
      if (g.epi == 2){
        uint2 p;
        p.x = pk2(acc[m][n][0], acc[m][n][1]);
        p.y = pk2(acc[m][n][2], acc[m][n][3]);
        *(uint2*)&g.Cb[(size_t)col * g.ldc + rbase] = p;
      } else {
        #pragma unroll
        for (int j = 0; j < 4; j++){
          float v = acc[m][n][j];
          size_t o = (size_t)(rbase + j) * g.ldc + col;
          switch (g.epi){
            case 0: g.Cf[o] = v; break;
            case 1: g.Cb[o] = f2bf(v); break;
            default: atomicAdd(&g.Cf[o], v); break;
          }
        }
      }
    }
  }
}

// ---------- mix5: mcomb = sig(gate)*(lo0+lo1) + (1-sig)*(gl0+gl1) ----------
__global__ __launch_bounds__(256) void flm_mix5(
    const float* __restrict__ gr, const float* __restrict__ lo0, const float* __restrict__ lo1,
    const float* __restrict__ gl0, const float* __restrict__ gl1, u16* __restrict__ o)
{
  int i = blockIdx.x * 256 + threadIdx.x;
  float4 gv = ((const float4*)gr)[i];
  float4 l0 = ((const float4*)lo0)[i];
  float4 l1 = ((const float4*)lo1)[i];
  float4 b0 = ((const float4*)gl0)[i];
  float4 b1 = ((const float4*)gl1)[i];
  float sx = 1.f/(1.f+expf(-gv.x)), sy = 1.f/(1.f+expf(-gv.y));
  float sz = 1.f/(1.f+expf(-gv.z)), sw = 1.f/(1.f+expf(-gv.w));
  uint2 p;
  p.x = pk2(sx*(l0.x+l1.x) + (1.f-sx)*(b0.x+b1.x), sy*(l0.y+l1.y) + (1.f-sy)*(b0.y+b1.y));
  p.y = pk2(sz*(l0.z+l1.z) + (1.f-sz)*(b0.z+b1.z), sw*(l0.w+l1.w) + (1.f-sw)*(b0.w+b1.w));
  ((uint2*)o)[i] = p;
}

// ---------- mix (fallback): mcomb = sig(gate)*lo + (1-sig)*gl ----------
__global__ __launch_bounds__(256) void flm_mix(
    const float* __restrict__ gr, const float* __restrict__ lo,
    const float* __restrict__ gl, u16* __restrict__ o)
{
  int i = blockIdx.x * 256 + threadIdx.x;
  float4 gv = ((const float4*)gr)[i];
  float4 lv = ((const float4*)lo)[i];
  float4 bv = ((const float4*)gl)[i];
  float sx = 1.f/(1.f+expf(-gv.x)), sy = 1.f/(1.f+expf(-gv.y));
  float sz = 1.f/(1.f+expf(-gv.z)), sw = 1.f/(1.f+expf(-gv.w));
  uint2 p;
  p.x = pk2(sx*lv.x + (1.f-sx)*bv.x, sy*lv.y + (1.f-sy)*bv.y);
  p.y = pk2(sz*lv.z + (1.f-sz)*bv.z, sw*lv.w + (1.f-sw)*bv.w);
  ((uint2*)o)[i] = p;
}

// ---------- silu fuse (bf16 in/out): sbuf = silu(g)*u ----------
__global__ __launch_bounds__(256) void flm_silu(
    const u16* __restrict__ gg, const u16* __restrict__ uu, u16* __restrict__ o)
{
  int i = blockIdx.x * 256 + threadIdx.x;
  uint2 gv = ((const uint2*)gg)[i];
  uint2 uv = ((const uint2*)uu)[i];
  float g0 = bf2f((u16)gv.x), g1 = bf2f((u16)(gv.x >> 16));
  float g2 = bf2f((u16)gv.y), g3 = bf2f((u16)(gv.y >> 16));
  float u0 = bf2f((u16)uv.x), u1 = bf2f((u16)(uv.x >> 16));
  float u2 = bf2f((u16)uv.y), u3 = bf2f((u16)(uv.y >> 16));
  float a = g0 / (1.f + expf(-g0)) * u0;
  float b = g1 / (1.f + expf(-g1)) * u1;
  float c = g2 / (1.f + expf(-g2)) * u2;
  float d = g3 / (1.f + expf(-g3)) * u3;
  uint2 p; p.x = pk2(a, b); p.y = pk2(c, d);
  ((uint2*)o)[i] = p;
}

// ---------- embedding gather + rmsnorm -> f32 h ----------
__global__ __launch_bounds__(256) void flm_embed(
    const int* __restrict__ x, const float* __restrict__ embed,
    const float* __restrict__ w, float* __restrict__ h)
{
  int t = blockIdx.x, tid = threadIdx.x;
  int tok = x[t];
  float4 v = ((const float4*)(embed + (size_t)tok * 1024))[tid];
  float ss = v.x*v.x + v.y*v.y + v.z*v.z + v.w*v.w;
  ss = wsum(ss);
  __shared__ float red[4];
  if ((tid & 63) == 0) red[tid >> 6] = ss;
  __syncthreads();
  float inv = rsqrtf((red[0]+red[1]+red[2]+red[3]) * (1.f/1024.f) + 1e-6f);
  float4 wv = ((const float4*)w)[tid];
  float4 o; o.x = v.x*inv*wv.x; o.y = v.y*inv*wv.y; o.z = v.z*inv*wv.z; o.w = v.w*inv*wv.w;
  ((float4*)(h + (size_t)t * 1024))[tid] = o;
}

// ---------- rmsnorm: h(f32) -> up to two bf16 outputs ----------
__global__ __launch_bounds__(256) void flm_rms(
    const float* __restrict__ h, const float* __restrict__ w1, const float* __restrict__ w2,
    u16* __restrict__ o1, u16* __restrict__ o2)
{
  int t = blockIdx.x, tid = threadIdx.x;
  float4 v = ((const float4*)(h + (size_t)t * 1024))[tid];
  float ss = v.x*v.x + v.y*v.y + v.z*v.z + v.w*v.w;
  ss = wsum(ss);
  __shared__ float red[4];
  if ((tid & 63) == 0) red[tid >> 6] = ss;
  __syncthreads();
  float inv = rsqrtf((red[0]+red[1]+red[2]+red[3]) * (1.f/1024.f) + 1e-6f);
  {
    float4 wv = ((const float4*)w1)[tid];
    uint2 p; p.x = pk2(v.x*inv*wv.x, v.y*inv*wv.y); p.y = pk2(v.z*inv*wv.z, v.w*inv*wv.w);
    ((uint2*)(o1 + (size_t)t * 1024))[tid] = p;
  }
  if (o2 != nullptr){
    float4 wv = ((const float4*)w2)[tid];
    uint2 p; p.x = pk2(v.x*inv*wv.x, v.y*inv*wv.y); p.y = pk2(v.z*inv*wv.z, v.w*inv*wv.w);
    ((uint2*)(o2 + (size_t)t * 1024))[tid] = p;
  }
}

// ---------- fused beta + k/q normalize, 4 waves/block (wave w: heads 4w..4w+3) ----------
__global__ __launch_bounds__(256) void flm_betanorm(
    const u16* __restrict__ h2, const float* __restrict__ bw, float* __restrict__ beta,
    u16* __restrict__ keys, u16* __restrict__ queries)
{
  int t = blockIdx.x, tid = threadIdx.x, lane = tid & 63, w = tid >> 6;
  float hv[16];
  #pragma unroll
  for (int i = 0; i < 16; i++) hv[i] = bf2f(h2[(size_t)t*1024 + i*64 + lane]);
  #pragma unroll
  for (int hh = 0; hh < 4; hh++){
    int h = w*4 + hh;
    float p = 0.f;
    #pragma unroll
    for (int i = 0; i < 16; i++) p += hv[i] * bw[h*1024 + i*64 + lane];
    p = wsum(p);
    if (lane == 0) beta[t*16 + h] = 1.f / (1.f + expf(-p));
    size_t idx = (size_t)t * 1024 + h * 64 + lane;
    float v = bf2f(keys[idx]);
    keys[idx] = f2bf(v / fmaxf(sqrtf(wsum(v * v)), 1e-12f));
    float q = bf2f(queries[idx]);
    queries[idx] = f2bf(q / fmaxf(sqrtf(wsum(q * q)), 1e-12f));
  }
}

// ---------- merged attention: z=0 -> SWA, z=1 -> delta ----------
// qkvb: [T][2048] (q | k). qvT/valT: [1024 d][1024 t] transposed V buffers.
__global__ __launch_bounds__(256) void flm_attn(
    const u16* __restrict__ qkvb, const u16* __restrict__ qvT,
    const u16* __restrict__ keys, const u16* __restrict__ valT, const u16* __restrict__ queries,
    const float* __restrict__ beta, u16* __restrict__ aout, u16* __restrict__ dout)
{
  __shared__ u16 sK[64][72];
  __shared__ u16 sVt[64][72];
  __shared__ u16 sP[4][16][72];
  const int tid = threadIdx.x, lane = tid & 63, w = tid >> 6;
  const int qt = blockIdx.x, h = blockIdx.y;
  const int base = h * 64;
  const int ri = w*16 + (lane>>4)*4;

  if (blockIdx.z == 0){
    bfv8 aq[2];
    {
      int qrow = qt*64 + w*16 + (lane & 15);
      #pragma unroll
      for (int kk = 0; kk < 2; kk++)
        aq[kk] = *(const bfv8*)(qkvb + (size_t)qrow*2048 + base + kk*32 + (lane>>4)*8);
    }
    f32x4 acc_o[4];
    float m_r[4], l_r[4];
    #pragma unroll
    for (int n = 0; n < 4; n++) acc_o[n] = (f32x4){0.f,0.f,0.f,0.f};
    #pragma unroll
    for (int r = 0; r < 4; r++){ m_r[r] = -1e30f; l_r[r] = 0.f; }
    const int jt0 = (qt >= 4) ? qt - 4 : 0;

    for (int jt = qt; jt >= jt0; jt--){
      #pragma unroll
      for (int i = 0; i < 2; i++){
        int idx = tid + i*256;
        int r = idx >> 3, c = (idx & 7) * 8;
        *(uint4*)&sK[r][c] = *(const uint4*)(qkvb + (size_t)(jt*64+r)*2048 + 1024 + base + c);
        *(uint4*)&sVt[r][c] = *(const uint4*)(qvT + (size_t)(base + r)*1024 + jt*64 + c);
      }
      __syncthreads();

      f32x4 sv[4];
      #pragma unroll
      for (int n = 0; n < 4; n++) sv[n] = (f32x4){0.f,0.f,0.f,0.f};
      #pragma unroll
      for (int kk = 0; kk < 2; kk++){
        #pragma unroll
        for (int n = 0; n < 4; n++){
          bfv8 bk = *(const bfv8*)&sK[n*16 + (lane & 15)][(lane>>4)*8 + kk*32];
          sv[n] = __builtin_amdgcn_mfma_f32_16x16x32_bf16(aq[kk], bk, sv[n], 0, 0, 0);
        }
      }
      #pragma unroll
      for (int n = 0; n < 4; n++){
        int cj = n*16 + (lane & 15);
        #pragma unroll
        for (int r = 0; r < 4; r++){
          float s = sv[n][r] * 0.125f;
          if (jt == qt)      { if (cj > ri + r) s = -1e30f; }
          else if (jt == jt0 && qt - jt0 == 4) { if (cj <= ri + r) s = -1e30f; }
          sv[n][r] = s;
        }
      }
      float pv[4][4], scl[4];
      #pragma unroll
      for (int r = 0; r < 4; r++){
        float mx = -1e30f;
        #pragma unroll
        for (int n = 0; n < 4; n++) mx = fmaxf(mx, sv[n][r]);
        #pragma unroll
        for (int m = 1; m < 16; m <<= 1) mx = fmaxf(mx, __shfl_xor(mx, m, 64));
        float mn = fmaxf(m_r[r], mx);
        float sc = expf(m_r[r] - mn);
        m_r[r] = mn; scl[r] = sc;
        float rs = 0.f;
        #pragma unroll
        for (int n = 0; n < 4; n++){ float p = expf(sv[n][r] - mn); pv[n][r] = p; rs += p; }
        #pragma unroll
        for (int m = 1; m < 16; m <<= 1) rs += __shfl_xor(rs, m, 64);
        l_r[r] = l_r[r] * sc + rs;
      }
      #pragma unroll
      for (int n = 0; n < 4; n++){
        #pragma unroll
        for (int r = 0; r < 4; r++){
          acc_o[n][r] *= scl[r];
          sP[w][(lane>>4)*4 + r][n*16 + (lane & 15)] = f2bf(pv[n][r]);
        }
      }
      #pragma unroll
      for (int kk = 0; kk < 2; kk++){
        bfv8 ap = *(const bfv8*)&sP[w][lane & 15][(lane>>4)*8 + kk*32];
        #pragma unroll
        for (int n = 0; n < 4; n++){
          bfv8 bv = *(const bfv8*)&sVt[n*16 + (lane & 15)][(lane>>4)*8 + kk*32];
          acc_o[n] = __builtin_amdgcn_mfma_f32_16x16x32_bf16(ap, bv, acc_o[n], 0, 0, 0);
        }
      }
      __syncthreads();
    }

    #pragma unroll
    for (int n = 0; n < 4; n++){
      int col = base + n*16 + (lane & 15);
      #pragma unroll
      for (int r = 0; r < 4; r++){
        int row = qt*64 + ri + r;
        aout[(size_t)row*1024 + col] = f2bf(acc_o[n][r] / l_r[r]);
      }
    }
  } else {
    bfv8 aq[2];
    {
      int qrow = qt*64 + w*16 + (lane & 15);
      #pragma unroll
      for (int kk = 0; kk < 2; kk++)
        aq[kk] = *(const bfv8*)(queries + (size_t)qrow*1024 + base + kk*32 + (lane>>4)*8);
    }
    f32x4 acc_o[4];
    #pragma unroll
    for (int n = 0; n < 4; n++) acc_o[n] = (f32x4){0.f,0.f,0.f,0.f};

    for (int jt = qt; jt < 16; jt++){
      #pragma unroll
      for (int i = 0; i < 2; i++){
        int idx = tid + i*256;
        int r = idx >> 3, c = (idx & 7) * 8;
        *(uint4*)&sK[r][c] = *(const uint4*)(keys + (size_t)(jt*64+r)*1024 + base + c);
        *(uint4*)&sVt[r][c] = *(const uint4*)(valT + (size_t)(base + r)*1024 + jt*64 + c);
      }
      __syncthreads();

      f32x4 sv[4];
      #pragma unroll
      for (int n = 0; n < 4; n++) sv[n] = (f32x4){0.f,0.f,0.f,0.f};
      #pragma unroll
      for (int kk = 0; kk < 2; kk++){
        #pragma unroll
        for (int n = 0; n < 4; n++){
          bfv8 bk = *(const bfv8*)&sK[n*16 + (lane & 15)][(lane>>4)*8 + kk*32];
          sv[n] = __builtin_amdgcn_mfma_f32_16x16x32_bf16(aq[kk], bk, sv[n], 0, 0, 0);
        }
      }
      #pragma unroll
      for (int n = 0; n < 4; n++){
        int cj = n*16 + (lane & 15);
        #pragma unroll
        for (int r = 0; r < 4; r++){
          float p = sv[n][r] * 0.125f;
          if (jt == qt && cj < ri + r) p = 0.f;
          sP[w][(lane>>4)*4 + r][n*16 + (lane & 15)] = f2bf(p);
        }
      }
      #pragma unroll
      for (int kk = 0; kk < 2; kk++){
        bfv8 ap = *(const bfv8*)&sP[w][lane & 15][(lane>>4)*8 + kk*32];
        #pragma unroll
        for (int n = 0; n < 4; n++){
          bfv8 bv = *(const bfv8*)&sVt[n*16 + (lane & 15)][(lane>>4)*8 + kk*32];
          acc_o[n] = __builtin_amdgcn_mfma_f32_16x16x32_bf16(ap, bv, acc_o[n], 0, 0, 0);
        }
      }
      __syncthreads();
    }

    #pragma unroll
    for (int n = 0; n < 4; n++){
      int col = base + n*16 + (lane & 15);
      #pragma unroll
      for (int r = 0; r < 4; r++){
        int row = qt*64 + ri + r;
        float b = beta[row*16 + h];
        float v = bf2f(valT[(size_t)col*1024 + row]);
        dout[(size_t)row*1024 + col] = f2bf(acc_o[n][r] + b * v);
      }
    }
  }
}

// ---------- host helpers ----------
static GDesc mkd(const u16* A, int lda, const float* Bw, int ldb,
                 float* Cf, u16* Cb, int ldc,
                 int kbeg, int kend, int blk0, int epi){
  GDesc d; d.A=A; d.Bw=Bw; d.Cf=Cf; d.Cb=Cb;
  d.lda=lda; d.ldb=ldb; d.ldc=ldc; d.kbeg=kbeg; d.kend=kend; d.blk0=blk0; d.epi=epi; d.pad=0;
  return d;
}

extern "C" void kernel_launch(void* const* d_in, const int* in_sizes, int n_in,
                              void* d_out, int out_size, void* d_ws, size_t ws_size,
                              hipStream_t stream)
{
  (void)in_sizes; (void)n_in; (void)out_size;
  const int*   x        = (const int*)d_in[0];
  const float* embed    = (const float*)d_in[1];
  const float* ln_in_w  = (const float*)d_in[2];
  const float* ln1_w    = (const float*)d_in[3];
  const float* lnd_w    = (const float*)d_in[4];
  const float* qkv_w    = (const float*)d_in[5];
  const float* swa_out_w= (const float*)d_in[6];
  const float* k_w      = (const float*)d_in[7];
  const float* v_w      = (const float*)d_in[8];
  const float* q_w      = (const float*)d_in[9];
  const float* beta_w   = (const float*)d_in[10];
  const float* mem_out_w= (const float*)d_in[11];
  const float* gate_w   = (const float*)d_in[12];
  const float* comb_w   = (const float*)d_in[13];
  const float* ln2_w    = (const float*)d_in[14];
  const float* wg       = (const float*)d_in[15];
  const float* wu       = (const float*)d_in[16];
  const float* wo       = (const float*)d_in[17];
  const float* ln_out_w = (const float*)d_in[18];
  float* out = (float*)d_out;

  char* ws = (char*)d_ws;
  const size_t KB = 1024, MB = 1u << 20;
  float* h       = (float*)(ws + 0);
  u16*   h1      = (u16*)  (ws + 4*MB);
  u16*   h2      = (u16*)  (ws + 6*MB);
  u16*   qkvb    = (u16*)  (ws + 8*MB);
  u16*   qvT     = (u16*)  (ws + 12*MB);
  u16*   keys    = (u16*)  (ws + 14*MB);
  u16*   valT    = (u16*)  (ws + 16*MB);
  u16*   queries = (u16*)  (ws + 18*MB);
  float* beta    = (float*)(ws + 20*MB);
  u16*   attn    = (u16*)  (ws + 20*MB + 256*KB);
  u16*   delt    = (u16*)  (ws + 22*MB + 256*KB);
  float* lo0     = (float*)(ws + 24*MB + 256*KB);
  float* lo1     = (float*)(ws + 28*MB + 256*KB);
  float* gl0     = (float*)(ws + 32*MB + 256*KB);
  float* gl1     = (float*)(ws + 36*MB + 256*KB);
  float* gbuf    = (float*)(ws + 40*MB + 256*KB);
  u16*   mcomb   = (u16*)  (ws + 44*MB + 256*KB);
  u16*   hn      = (u16*)  (ws + 46*MB + 256*KB);
  u16*   g16     = (u16*)  (ws + 4*MB);
  u16*   u16b    = (u16*)  (ws + 12*MB);
  u16*   sbuf    = (u16*)  (ws + 20*MB);

  // bf16 weight region
  u16* wb = (u16*)(ws + 48*MB + 512*KB);
  size_t off = 0; auto nx = [&](size_t n){ size_t o = off; off += n; return o; };
  const size_t nEmb = 32768000ULL, nQkv = 12582912ULL, nSq = 4194304ULL, nFf = 16777216ULL;
  u16* wemb  = wb + nx(nEmb);
  u16* wqkv  = wb + nx(nQkv);
  u16* wswa  = wb + nx(nSq);
  u16* wk    = wb + nx(nSq);
  u16* wv    = wb + nx(nSq);
  u16* wq    = wb + nx(nSq);
  u16* wmem  = wb + nx(nSq);
  u16* wgate = wb + nx(nSq);
  u16* wcomb = wb + nx(nSq);
  u16* wwg   = wb + nx(nFf);
  u16* wwu   = wb + nx(nFf);
  u16* wwo   = wb + nx(nFf);
  const size_t NEED = 48*MB + 512*KB + off * 2;
  const bool bw = (ws_size >= NEED);

  auto MG = [&](int nblk, GBatch& gbv){
    if (bw) flm_mgemm<true><<<nblk, 512, 0, stream>>>(gbv);
    else    flm_mgemm<false><<<nblk, 512, 0, stream>>>(gbv);
  };

  if (bw){
    CBatch cb;
    const float* srcs[12] = {embed, qkv_w, swa_out_w, k_w, v_w, q_w,
                             mem_out_w, gate_w, comb_w, wg, wu, wo};
    const size_t ns[12] = {nEmb, nQkv, nSq, nSq, nSq, nSq, nSq, nSq, nSq, nFf, nFf, nFf};
    long long acc4 = 0;
    for (int i = 0; i < 12; i++){ cb.s[i] = srcs[i]; cb.p4[i] = acc4; acc4 += (long long)(ns[i] >> 2); }
    cb.p4[12] = acc4; cb.dst = wb;
    flm_conv<<<dim3(1024, 12), 256, 0, stream>>>(cb);
  }

  flm_embed<<<1024, 256, 0, stream>>>(x, embed, ln_in_w, h);

  for (int l = 0; l < 4; l++){
    const size_t lq = (size_t)l * 3145728, ls = (size_t)l * 1048576, lf = (size_t)l * 4194304;
    const float* Wqkv  = bw ? (const float*)(wqkv  + lq) : qkv_w     + lq;
    const float* WqkvV = bw ? (const float*)(wqkv  + lq + 2048*1024ULL) : qkv_w + lq + 2048*1024ULL;
    const float* Wk    = bw ? (const float*)(wk    + ls) : k_w       + ls;
    const float* Wv    = bw ? (const float*)(wv    + ls) : v_w       + ls;
    const float* Wq    = bw ? (const float*)(wq    + ls) : q_w       + ls;
    const float* Wswa  = bw ? (const float*)(wswa  + ls) : swa_out_w + ls;
    const float* Wmem  = bw ? (const float*)(wmem  + ls) : mem_out_w + ls;
    const float* Wgate = bw ? (const float*)(wgate + ls) : gate_w    + ls;
    const float* Wcomb = bw ? (const float*)(wcomb + ls) : comb_w    + ls;
    const float* Wwg   = bw ? (const float*)(wwg   + lf) : wg        + lf;
    const float* Wwu   = bw ? (const float*)(wwu   + lf) : wu        + lf;
    const float* Wwo   = bw ? (const float*)(wwo   + lf) : wo        + lf;

    flm_rms<<<1024, 256, 0, stream>>>(h, ln1_w + l*1024, lnd_w + l*1024, h1, h2);

    // batch1: qk(128) + qvT(64,T) + k(64) + valT(64,T) + q(64) + gate(64) = 448, all K=1024
    {
      GBatch gb;
      gb.d[0] = mkd(h1, 1024, Wqkv,  1024, nullptr, qkvb,    2048, 0, 1024, 0,   1);
      gb.d[1] = mkd(h1, 1024, WqkvV, 1024, nullptr, qvT,     1024, 0, 1024, 128, 2);
      gb.d[2] = mkd(h2, 1024, Wk,    1024, nullptr, keys,    1024, 0, 1024, 192, 1);
      gb.d[3] = mkd(h2, 1024, Wv,    1024, nullptr, valT,    1024, 0, 1024, 256, 2);
      gb.d[4] = mkd(h2, 1024, Wq,    1024, nullptr, queries, 1024, 0, 1024, 320, 1);
      gb.d[5] = mkd(h1, 1024, Wgate, 1024, gbuf,    nullptr, 1024, 0, 1024, 384, 0);
      gb.ng = 6; gb.total = 448;
      MG(448, gb);
    }
    flm_betanorm<<<1024, 256, 0, stream>>>(h2, beta_w + (size_t)l*16*1024, beta, keys, queries);
    flm_attn<<<dim3(16, 16, 2), 256, 0, stream>>>(qkvb, qvT, keys, valT, queries, beta, attn, delt);

    if (bw){
      // batch2: {swa,mem} x {K half} = 4 x 64 = 256 blocks, all K=512, plain stores
      GBatch gb;
      gb.d[0] = mkd(attn, 1024, Wswa, 1024, lo0, nullptr, 1024, 0,   512,  0,   0);
      gb.d[1] = mkd(attn, 1024, Wswa, 1024, lo1, nullptr, 1024, 512, 1024, 64,  0);
      gb.d[2] = mkd(delt, 1024, Wmem, 1024, gl0, nullptr, 1024, 0,   512,  128, 0);
      gb.d[3] = mkd(delt, 1024, Wmem, 1024, gl1, nullptr, 1024, 512, 1024, 192, 0);
      gb.d[4] = gb.d[3]; gb.d[4].blk0 = 0x7fffffff;
      gb.d[5] = gb.d[4];
      gb.ng = 4; gb.total = 256;
      MG(256, gb);
      flm_mix5<<<1024, 256, 0, stream>>>(gbuf, lo0, lo1, gl0, gl1, mcomb);
    } else {
      GBatch gb;
      gb.d[0] = mkd(attn, 1024, Wswa, 1024, lo0, nullptr, 1024, 0, 1024, 0, 0);
      gb.d[1] = mkd(delt, 1024, Wmem, 1024, gl0, nullptr, 1024, 0, 1024, 64, 0);
      gb.d[2] = gb.d[1]; gb.d[2].blk0 = 0x7fffffff;
      gb.d[3] = gb.d[2]; gb.d[4] = gb.d[2]; gb.d[5] = gb.d[2];
      gb.ng = 2; gb.total = 128;
      MG(128, gb);
      flm_mix<<<1024, 256, 0, stream>>>(gbuf, lo0, gl0, mcomb);
    }

    // comb: split-K x4 (homogeneous K=256), 256 blocks, atomicAdd into live f32 h
    {
      GBatch gb;
      for (int s = 0; s < 4; s++)
        gb.d[s] = mkd(mcomb, 1024, Wcomb, 1024, h, nullptr, 1024, s*256, (s+1)*256, s*64, 5);
      gb.d[4] = gb.d[3]; gb.d[4].blk0 = 0x7fffffff;
      gb.d[5] = gb.d[4];
      gb.ng = 4; gb.total = 256;
      MG(256, gb);
    }
    flm_rms<<<1024, 256, 0, stream>>>(h, ln2_w + l*1024, nullptr, hn, nullptr);
    // batch3: wg -> g16 (256) + wu -> u16b (256) = 512, bf16 stores
    {
      GBatch gb;
      gb.d[0] = mkd(hn, 1024, Wwg, 1024, nullptr, g16, 4096, 0, 1024, 0, 1);
      gb.d[1] = mkd(hn, 1024, Wwu, 1024, nullptr, u16b, 4096, 0, 1024, 256, 1);
      gb.d[2] = gb.d[1]; gb.d[2].blk0 = 0x7fffffff;
      gb.d[3] = gb.d[2]; gb.d[4] = gb.d[2]; gb.d[5] = gb.d[2];
      gb.ng = 2; gb.total = 512;
      MG(512, gb);
    }
    flm_silu<<<4096, 256, 0, stream>>>(g16, u16b, sbuf);
    // wo: split-K x4, atomicAdd into h
    {
      GBatch gb;
      for (int s = 0; s < 4; s++)
        gb.d[s] = mkd(sbuf, 4096, Wwo, 4096, h, nullptr, 1024, s*1024, (s+1)*1024, s*64, 5);
      gb.d[4] = gb.d[3]; gb.d[4].blk0 = 0x7fffffff;
      gb.d[5] = gb.d[4];
      gb.ng = 4; gb.total = 256;
      MG(256, gb);
    }
  }

  flm_rms<<<1024, 256, 0, stream>>>(h, ln_out_w, nullptr, hn, nullptr);
  // head: 250 col-tiles x 8 row-tiles = 2000 blocks
  {
    GBatch gb;
    gb.d[0] = mkd(hn, 1024, bw ? (const float*)wemb : embed, 1024, out, nullptr, 32000,
                  0, 1024, 0, 0);
    gb.d[1] = gb.d[0]; gb.d[1].blk0 = 0x7fffffff;
    gb.d[2] = gb.d[1]; gb.d[3] = gb.d[1]; gb.d[4] = gb.d[1]; gb.d[5] = gb.d[1];
    gb.ng = 1; gb.total = 2000;
    MG(2000, gb);
  }
}

// Round 17
// 913.291 us; speedup vs baseline: 1.0101x; 1.0101x over previous
//
#include <hip/hip_runtime.h>

typedef unsigned short u16;
typedef unsigned int   u32;
typedef __attribute__((ext_vector_type(8))) __bf16 bfv8;
typedef __attribute__((ext_vector_type(4))) float  f32x4;
typedef __attribute__((ext_vector_type(4))) u32    u32x4;

// ---------- helpers ----------
__device__ __forceinline__ u16 f2bf(float f){
  __bf16 b = (__bf16)f;                       // native v_cvt (RNE)
  return __builtin_bit_cast(u16, b);
}
__device__ __forceinline__ float bf2f(u16 b){
  return __builtin_bit_cast(float, ((u32)b) << 16);
}
__device__ __forceinline__ u32 pk2(float a, float b){
  return (u32)f2bf(a) | ((u32)f2bf(b) << 16);
}
__device__ __forceinline__ float wsum(float v){
  #pragma unroll
  for (int m = 32; m > 0; m >>= 1) v += __shfl_xor(v, m, 64);
  return v;
}
__device__ __forceinline__ void gload16(const void* g, void* l){
  __builtin_amdgcn_global_load_lds((const __attribute__((address_space(1))) void*)g,
                                   (__attribute__((address_space(3))) void*)l, 16, 0, 0);
}

// ---------- weight f32 -> bf16 conversion (nontemporal, 32B/thread/iter) ----------
struct CBatch { const float* s[12]; long long p4[13]; u16* dst; };
__global__ __launch_bounds__(256) void flm_conv(CBatch cb)
{
  const int seg = blockIdx.y;
  const long long base = cb.p4[seg];                 // float4 units
  const long long n8 = (cb.p4[seg + 1] - base) >> 1; // 8-float units
  const f32x4* __restrict__ src = (const f32x4*)cb.s[seg];
  u32x4* __restrict__ dst = (u32x4*)cb.dst + (base >> 1);
  for (long long i = (long long)blockIdx.x * 256 + threadIdx.x; i < n8;
       i += (long long)gridDim.x * 256){
    f32x4 v0 = __builtin_nontemporal_load(src + 2*i);
    f32x4 v1 = __builtin_nontemporal_load(src + 2*i + 1);
    u32x4 p;
    p.x = pk2(v0.x, v0.y); p.y = pk2(v0.z, v0.w);
    p.z = pk2(v1.x, v1.y); p.w = pk2(v1.z, v1.w);
    __builtin_nontemporal_store(p, dst + i);
  }
}

// ---------- multi-GEMM (512 thr, 8 waves, 128x128 tile, acc 4x2/wave) ----------
// BW=true: bf16 A and W via global_load_lds + XOR swizzle (rule #21).
// epi: 0 = f32 store, 1 = bf16 store, 2 = bf16 TRANSPOSED store (C^T), 5 = f32 atomicAdd
struct GDesc {
  const u16* A; const float* Bw; float* Cf; u16* Cb;
  int lda, ldb, ldc, kbeg, kend, blk0, epi, pad;
};
struct GBatch { GDesc d[6]; int ng, total; };

template<bool BW>
__global__ __launch_bounds__(512) void flm_mgemm(GBatch gb)
{
  constexpr int LDK = BW ? 64 : 72;
  __shared__ u16 sA[128][LDK];
  __shared__ u16 sB[128][LDK];
  const int tid = threadIdx.x, lane = tid & 63, w = tid >> 6;

  const int T = gb.total, bid = blockIdx.x;
  const int q8 = T >> 3, r8 = T & 7, xc = bid & 7, of = bid >> 3;
  const int lin = (xc < r8 ? xc * (q8 + 1) : r8 * (q8 + 1) + (xc - r8) * q8) + of;
  int di = 0;
  #pragma unroll
  for (int i = 1; i < 6; i++) if (i < gb.ng && lin >= gb.d[i].blk0) di = i;
  const GDesc g = gb.d[di];
  const int local = lin - g.blk0;
  const int row0 = (local & 7) * 128;
  const int col0 = (local >> 3) * 128;
  const int wr = (w >> 2) * 64, wc = (w & 3) * 32;

  f32x4 acc[4][2];
  #pragma unroll
  for (int m = 0; m < 4; m++)
    #pragma unroll
    for (int n = 0; n < 2; n++)
      acc[m][n] = (f32x4){0.f, 0.f, 0.f, 0.f};

  const int csw = ((lane & 7) ^ (lane >> 3)) * 8;   // inverse-swizzled src col (elems)
  const u16* B16 = (const u16*)g.Bw;

  for (int k0 = g.kbeg; k0 < g.kend; k0 += 64){
    if constexpr (BW){
      const u16* a0 = g.A + (size_t)(row0 + w*16 + (lane>>3)) * g.lda + k0 + csw;
      const u16* b0 = B16 + (size_t)(col0 + w*16 + (lane>>3)) * g.ldb + k0 + csw;
      gload16(a0,                     &sA[w*16    ][0]);
      gload16(a0 + (size_t)8*g.lda,   &sA[w*16 + 8][0]);
      gload16(b0,                     &sB[w*16    ][0]);
      gload16(b0 + (size_t)8*g.ldb,   &sB[w*16 + 8][0]);
    } else {
      #pragma unroll
      for (int i = 0; i < 2; i++){
        int idx = tid + i * 512;
        int r = idx >> 3, c = (idx & 7) * 8;
        *(uint4*)&sA[r][c] = *(const uint4*)(g.A + (size_t)(row0 + r) * g.lda + k0 + c);
      }
      #pragma unroll
      for (int i = 0; i < 4; i++){
        int idx = tid + i * 512;
        int r = idx >> 4, c = (idx & 15) * 4;
        float4 v = *(const float4*)(g.Bw + (size_t)(col0 + r) * g.ldb + k0 + c);
        uint2 p; p.x = pk2(v.x, v.y); p.y = pk2(v.z, v.w);
        *(uint2*)&sB[r][c] = p;
      }
    }
    __syncthreads();
    #pragma unroll
    for (int kk = 0; kk < 2; kk++){
      bfv8 af[4], bfr[2];
      #pragma unroll
      for (int m = 0; m < 4; m++){
        int row = wr + m*16 + (lane & 15);
        if constexpr (BW){
          int slot = (kk*4 + (lane >> 4)) ^ (row & 7);
          af[m] = *(const bfv8*)((const char*)sA + row*128 + slot*16);
        } else {
          af[m] = *(const bfv8*)&sA[row][kk*32 + (lane >> 4) * 8];
        }
      }
      #pragma unroll
      for (int n = 0; n < 2; n++){
        int row = wc + n*16 + (lane & 15);
        if constexpr (BW){
          int slot = (kk*4 + (lane >> 4)) ^ (row & 7);
          bfr[n] = *(const bfv8*)((const char*)sB + row*128 + slot*16);
        } else {
          bfr[n] = *(const bfv8*)&sB[row][kk*32 + (lane >> 4) * 8];
        }
      }
      #pragma unroll
      for (int m = 0; m < 4; m++)
        #pragma unroll
        for (int n = 0; n < 2; n++)
          acc[m][n] = __builtin_amdgcn_mfma_f32_16x16x32_bf16(af[m], bfr[n], acc[m][n], 0, 0, 0);
    }
    __syncthreads();
  }

  #pragma unroll
  for (int m = 0; m < 4; m++){
    int rbase = row0 + wr + m*16 + (lane >> 4) * 4;
    #pragma unroll
    for (int n = 0; n < 2; n++){
      int col = col0 + wc + n*16 + (lane & 15);
      if (g.epi == 2){
        uint2 p;
        p.x = pk2(acc[m][n][0], acc[m][n][1]);
        p.y = pk2(acc[m][n][2], acc[m][n][3]);
        *(uint2*)&g.Cb[(size_t)col * g.ldc + rbase] = p;
      } else {
        #pragma unroll
        for (int j = 0; j < 4; j++){
          float v = acc[m][n][j];
          size_t o = (size_t)(rbase + j) * g.ldc + col;
          switch (g.epi){
            case 0: g.Cf[o] = v; break;
            case 1: g.Cb[o] = f2bf(v); break;
            default: atomicAdd(&g.Cf[o], v); break;
          }
        }
      }
    }
  }
}

// ---------- mix5: mcomb = sig(gate)*(lo0+lo1) + (1-sig)*(gl0+gl1) ----------
__global__ __launch_bounds__(256) void flm_mix5(
    const float* __restrict__ gr, const float* __restrict__ lo0, const float* __restrict__ lo1,
    const float* __restrict__ gl0, const float* __restrict__ gl1, u16* __restrict__ o)
{
  int i = blockIdx.x * 256 + threadIdx.x;
  float4 gv = ((const float4*)gr)[i];
  float4 l0 = ((const float4*)lo0)[i];
  float4 l1 = ((const float4*)lo1)[i];
  float4 b0 = ((const float4*)gl0)[i];
  float4 b1 = ((const float4*)gl1)[i];
  float sx = 1.f/(1.f+expf(-gv.x)), sy = 1.f/(1.f+expf(-gv.y));
  float sz = 1.f/(1.f+expf(-gv.z)), sw = 1.f/(1.f+expf(-gv.w));
  uint2 p;
  p.x = pk2(sx*(l0.x+l1.x) + (1.f-sx)*(b0.x+b1.x), sy*(l0.y+l1.y) + (1.f-sy)*(b0.y+b1.y));
  p.y = pk2(sz*(l0.z+l1.z) + (1.f-sz)*(b0.z+b1.z), sw*(l0.w+l1.w) + (1.f-sw)*(b0.w+b1.w));
  ((uint2*)o)[i] = p;
}

// ---------- mix (fallback): mcomb = sig(gate)*lo + (1-sig)*gl ----------
__global__ __launch_bounds__(256) void flm_mix(
    const float* __restrict__ gr, const float* __restrict__ lo,
    const float* __restrict__ gl, u16* __restrict__ o)
{
  int i = blockIdx.x * 256 + threadIdx.x;
  float4 gv = ((const float4*)gr)[i];
  float4 lv = ((const float4*)lo)[i];
  float4 bv = ((const float4*)gl)[i];
  float sx = 1.f/(1.f+expf(-gv.x)), sy = 1.f/(1.f+expf(-gv.y));
  float sz = 1.f/(1.f+expf(-gv.z)), sw = 1.f/(1.f+expf(-gv.w));
  uint2 p;
  p.x = pk2(sx*lv.x + (1.f-sx)*bv.x, sy*lv.y + (1.f-sy)*bv.y);
  p.y = pk2(sz*lv.z + (1.f-sz)*bv.z, sw*lv.w + (1.f-sw)*bv.w);
  ((uint2*)o)[i] = p;
}

// ---------- silu fuse (bf16 in/out): sbuf = silu(g)*u ----------
__global__ __launch_bounds__(256) void flm_silu(
    const u16* __restrict__ gg, const u16* __restrict__ uu, u16* __restrict__ o)
{
  int i = blockIdx.x * 256 + threadIdx.x;
  uint2 gv = ((const uint2*)gg)[i];
  uint2 uv = ((const uint2*)uu)[i];
  float g0 = bf2f((u16)gv.x), g1 = bf2f((u16)(gv.x >> 16));
  float g2 = bf2f((u16)gv.y), g3 = bf2f((u16)(gv.y >> 16));
  float u0 = bf2f((u16)uv.x), u1 = bf2f((u16)(uv.x >> 16));
  float u2 = bf2f((u16)uv.y), u3 = bf2f((u16)(uv.y >> 16));
  float a = g0 / (1.f + expf(-g0)) * u0;
  float b = g1 / (1.f + expf(-g1)) * u1;
  float c = g2 / (1.f + expf(-g2)) * u2;
  float d = g3 / (1.f + expf(-g3)) * u3;
  uint2 p; p.x = pk2(a, b); p.y = pk2(c, d);
  ((uint2*)o)[i] = p;
}

// ---------- embedding gather + rmsnorm -> f32 h ----------
__global__ __launch_bounds__(256) void flm_embed(
    const int* __restrict__ x, const float* __restrict__ embed,
    const float* __restrict__ w, float* __restrict__ h)
{
  int t = blockIdx.x, tid = threadIdx.x;
  int tok = x[t];
  float4 v = ((const float4*)(embed + (size_t)tok * 1024))[tid];
  float ss = v.x*v.x + v.y*v.y + v.z*v.z + v.w*v.w;
  ss = wsum(ss);
  __shared__ float red[4];
  if ((tid & 63) == 0) red[tid >> 6] = ss;
  __syncthreads();
  float inv = rsqrtf((red[0]+red[1]+red[2]+red[3]) * (1.f/1024.f) + 1e-6f);
  float4 wv = ((const float4*)w)[tid];
  float4 o; o.x = v.x*inv*wv.x; o.y = v.y*inv*wv.y; o.z = v.z*inv*wv.z; o.w = v.w*inv*wv.w;
  ((float4*)(h + (size_t)t * 1024))[tid] = o;
}

// ---------- rmsnorm: h(f32) -> up to two bf16 outputs ----------
__global__ __launch_bounds__(256) void flm_rms(
    const float* __restrict__ h, const float* __restrict__ w1, const float* __restrict__ w2,
    u16* __restrict__ o1, u16* __restrict__ o2)
{
  int t = blockIdx.x, tid = threadIdx.x;
  float4 v = ((const float4*)(h + (size_t)t * 1024))[tid];
  float ss = v.x*v.x + v.y*v.y + v.z*v.z + v.w*v.w;
  ss = wsum(ss);
  __shared__ float red[4];
  if ((tid & 63) == 0) red[tid >> 6] = ss;
  __syncthreads();
  float inv = rsqrtf((red[0]+red[1]+red[2]+red[3]) * (1.f/1024.f) + 1e-6f);
  {
    float4 wv = ((const float4*)w1)[tid];
    uint2 p; p.x = pk2(v.x*inv*wv.x, v.y*inv*wv.y); p.y = pk2(v.z*inv*wv.z, v.w*inv*wv.w);
    ((uint2*)(o1 + (size_t)t * 1024))[tid] = p;
  }
  if (o2 != nullptr){
    float4 wv = ((const float4*)w2)[tid];
    uint2 p; p.x = pk2(v.x*inv*wv.x, v.y*inv*wv.y); p.y = pk2(v.z*inv*wv.z, v.w*inv*wv.w);
    ((uint2*)(o2 + (size_t)t * 1024))[tid] = p;
  }
}

// ---------- fused beta + k/q normalize, 4 waves/block (wave w: heads 4w..4w+3) ----------
__global__ __launch_bounds__(256) void flm_betanorm(
    const u16* __restrict__ h2, const float* __restrict__ bw, float* __restrict__ beta,
    u16* __restrict__ keys, u16* __restrict__ queries)
{
  int t = blockIdx.x, tid = threadIdx.x, lane = tid & 63, w = tid >> 6;
  float hv[16];
  #pragma unroll
  for (int i = 0; i < 16; i++) hv[i] = bf2f(h2[(size_t)t*1024 + i*64 + lane]);
  #pragma unroll
  for (int hh = 0; hh < 4; hh++){
    int h = w*4 + hh;
    float p = 0.f;
    #pragma unroll
    for (int i = 0; i < 16; i++) p += hv[i] * bw[h*1024 + i*64 + lane];
    p = wsum(p);
    if (lane == 0) beta[t*16 + h] = 1.f / (1.f + expf(-p));
    size_t idx = (size_t)t * 1024 + h * 64 + lane;
    float v = bf2f(keys[idx]);
    keys[idx] = f2bf(v / fmaxf(sqrtf(wsum(v * v)), 1e-12f));
    float q = bf2f(queries[idx]);
    queries[idx] = f2bf(q / fmaxf(sqrtf(wsum(q * q)), 1e-12f));
  }
}

// ---------- merged attention: z=0 -> SWA, z=1 -> delta ----------
// qkvb: [T][2048] (q | k). qvT/valT: [1024 d][1024 t] transposed V buffers.
__global__ __launch_bounds__(256) void flm_attn(
    const u16* __restrict__ qkvb, const u16* __restrict__ qvT,
    const u16* __restrict__ keys, const u16* __restrict__ valT, const u16* __restrict__ queries,
    const float* __restrict__ beta, u16* __restrict__ aout, u16* __restrict__ dout)
{
  __shared__ u16 sK[64][72];
  __shared__ u16 sVt[64][72];
  __shared__ u16 sP[4][16][72];
  const int tid = threadIdx.x, lane = tid & 63, w = tid >> 6;
  const int qt = blockIdx.x, h = blockIdx.y;
  const int base = h * 64;
  const int ri = w*16 + (lane>>4)*4;

  if (blockIdx.z == 0){
    bfv8 aq[2];
    {
      int qrow = qt*64 + w*16 + (lane & 15);
      #pragma unroll
      for (int kk = 0; kk < 2; kk++)
        aq[kk] = *(const bfv8*)(qkvb + (size_t)qrow*2048 + base + kk*32 + (lane>>4)*8);
    }
    f32x4 acc_o[4];
    float m_r[4], l_r[4];
    #pragma unroll
    for (int n = 0; n < 4; n++) acc_o[n] = (f32x4){0.f,0.f,0.f,0.f};
    #pragma unroll
    for (int r = 0; r < 4; r++){ m_r[r] = -1e30f; l_r[r] = 0.f; }
    const int jt0 = (qt >= 4) ? qt - 4 : 0;

    for (int jt = qt; jt >= jt0; jt--){
      #pragma unroll
      for (int i = 0; i < 2; i++){
        int idx = tid + i*256;
        int r = idx >> 3, c = (idx & 7) * 8;
        *(uint4*)&sK[r][c] = *(const uint4*)(qkvb + (size_t)(jt*64+r)*2048 + 1024 + base + c);
        *(uint4*)&sVt[r][c] = *(const uint4*)(qvT + (size_t)(base + r)*1024 + jt*64 + c);
      }
      __syncthreads();

      f32x4 sv[4];
      #pragma unroll
      for (int n = 0; n < 4; n++) sv[n] = (f32x4){0.f,0.f,0.f,0.f};
      #pragma unroll
      for (int kk = 0; kk < 2; kk++){
        #pragma unroll
        for (int n = 0; n < 4; n++){
          bfv8 bk = *(const bfv8*)&sK[n*16 + (lane & 15)][(lane>>4)*8 + kk*32];
          sv[n] = __builtin_amdgcn_mfma_f32_16x16x32_bf16(aq[kk], bk, sv[n], 0, 0, 0);
        }
      }
      #pragma unroll
      for (int n = 0; n < 4; n++){
        int cj = n*16 + (lane & 15);
        #pragma unroll
        for (int r = 0; r < 4; r++){
          float s = sv[n][r] * 0.125f;
          if (jt == qt)      { if (cj > ri + r) s = -1e30f; }
          else if (jt == jt0 && qt - jt0 == 4) { if (cj <= ri + r) s = -1e30f; }
          sv[n][r] = s;
        }
      }
      float pv[4][4], scl[4];
      #pragma unroll
      for (int r = 0; r < 4; r++){
        float mx = -1e30f;
        #pragma unroll
        for (int n = 0; n < 4; n++) mx = fmaxf(mx, sv[n][r]);
        #pragma unroll
        for (int m = 1; m < 16; m <<= 1) mx = fmaxf(mx, __shfl_xor(mx, m, 64));
        float mn = fmaxf(m_r[r], mx);
        float sc = expf(m_r[r] - mn);
        m_r[r] = mn; scl[r] = sc;
        float rs = 0.f;
        #pragma unroll
        for (int n = 0; n < 4; n++){ float p = expf(sv[n][r] - mn); pv[n][r] = p; rs += p; }
        #pragma unroll
        for (int m = 1; m < 16; m <<= 1) rs += __shfl_xor(rs, m, 64);
        l_r[r] = l_r[r] * sc + rs;
      }
      #pragma unroll
      for (int n = 0; n < 4; n++){
        #pragma unroll
        for (int r = 0; r < 4; r++){
          acc_o[n][r] *= scl[r];
          sP[w][(lane>>4)*4 + r][n*16 + (lane & 15)] = f2bf(pv[n][r]);
        }
      }
      #pragma unroll
      for (int kk = 0; kk < 2; kk++){
        bfv8 ap = *(const bfv8*)&sP[w][lane & 15][(lane>>4)*8 + kk*32];
        #pragma unroll
        for (int n = 0; n < 4; n++){
          bfv8 bv = *(const bfv8*)&sVt[n*16 + (lane & 15)][(lane>>4)*8 + kk*32];
          acc_o[n] = __builtin_amdgcn_mfma_f32_16x16x32_bf16(ap, bv, acc_o[n], 0, 0, 0);
        }
      }
      __syncthreads();
    }

    #pragma unroll
    for (int n = 0; n < 4; n++){
      int col = base + n*16 + (lane & 15);
      #pragma unroll
      for (int r = 0; r < 4; r++){
        int row = qt*64 + ri + r;
        aout[(size_t)row*1024 + col] = f2bf(acc_o[n][r] / l_r[r]);
      }
    }
  } else {
    bfv8 aq[2];
    {
      int qrow = qt*64 + w*16 + (lane & 15);
      #pragma unroll
      for (int kk = 0; kk < 2; kk++)
        aq[kk] = *(const bfv8*)(queries + (size_t)qrow*1024 + base + kk*32 + (lane>>4)*8);
    }
    f32x4 acc_o[4];
    #pragma unroll
    for (int n = 0; n < 4; n++) acc_o[n] = (f32x4){0.f,0.f,0.f,0.f};

    for (int jt = qt; jt < 16; jt++){
      #pragma unroll
      for (int i = 0; i < 2; i++){
        int idx = tid + i*256;
        int r = idx >> 3, c = (idx & 7) * 8;
        *(uint4*)&sK[r][c] = *(const uint4*)(keys + (size_t)(jt*64+r)*1024 + base + c);
        *(uint4*)&sVt[r][c] = *(const uint4*)(valT + (size_t)(base + r)*1024 + jt*64 + c);
      }
      __syncthreads();

      f32x4 sv[4];
      #pragma unroll
      for (int n = 0; n < 4; n++) sv[n] = (f32x4){0.f,0.f,0.f,0.f};
      #pragma unroll
      for (int kk = 0; kk < 2; kk++){
        #pragma unroll
        for (int n = 0; n < 4; n++){
          bfv8 bk = *(const bfv8*)&sK[n*16 + (lane & 15)][(lane>>4)*8 + kk*32];
          sv[n] = __builtin_amdgcn_mfma_f32_16x16x32_bf16(aq[kk], bk, sv[n], 0, 0, 0);
        }
      }
      #pragma unroll
      for (int n = 0; n < 4; n++){
        int cj = n*16 + (lane & 15);
        #pragma unroll
        for (int r = 0; r < 4; r++){
          float p = sv[n][r] * 0.125f;
          if (jt == qt && cj < ri + r) p = 0.f;
          sP[w][(lane>>4)*4 + r][n*16 + (lane & 15)] = f2bf(p);
        }
      }
      #pragma unroll
      for (int kk = 0; kk < 2; kk++){
        bfv8 ap = *(const bfv8*)&sP[w][lane & 15][(lane>>4)*8 + kk*32];
        #pragma unroll
        for (int n = 0; n < 4; n++){
          bfv8 bv = *(const bfv8*)&sVt[n*16 + (lane & 15)][(lane>>4)*8 + kk*32];
          acc_o[n] = __builtin_amdgcn_mfma_f32_16x16x32_bf16(ap, bv, acc_o[n], 0, 0, 0);
        }
      }
      __syncthreads();
    }

    #pragma unroll
    for (int n = 0; n < 4; n++){
      int col = base + n*16 + (lane & 15);
      #pragma unroll
      for (int r = 0; r < 4; r++){
        int row = qt*64 + ri + r;
        float b = beta[row*16 + h];
        float v = bf2f(valT[(size_t)col*1024 + row]);
        dout[(size_t)row*1024 + col] = f2bf(acc_o[n][r] + b * v);
      }
    }
  }
}

// ---------- host helpers ----------
static GDesc mkd(const u16* A, int lda, const float* Bw, int ldb,
                 float* Cf, u16* Cb, int ldc,
                 int kbeg, int kend, int blk0, int epi){
  GDesc d; d.A=A; d.Bw=Bw; d.Cf=Cf; d.Cb=Cb;
  d.lda=lda; d.ldb=ldb; d.ldc=ldc; d.kbeg=kbeg; d.kend=kend; d.blk0=blk0; d.epi=epi; d.pad=0;
  return d;
}

extern "C" void kernel_launch(void* const* d_in, const int* in_sizes, int n_in,
                              void* d_out, int out_size, void* d_ws, size_t ws_size,
                              hipStream_t stream)
{
  (void)in_sizes; (void)n_in; (void)out_size;
  const int*   x        = (const int*)d_in[0];
  const float* embed    = (const float*)d_in[1];
  const float* ln_in_w  = (const float*)d_in[2];
  const float* ln1_w    = (const float*)d_in[3];
  const float* lnd_w    = (const float*)d_in[4];
  const float* qkv_w    = (const float*)d_in[5];
  const float* swa_out_w= (const float*)d_in[6];
  const float* k_w      = (const float*)d_in[7];
  const float* v_w      = (const float*)d_in[8];
  const float* q_w      = (const float*)d_in[9];
  const float* beta_w   = (const float*)d_in[10];
  const float* mem_out_w= (const float*)d_in[11];
  const float* gate_w   = (const float*)d_in[12];
  const float* comb_w   = (const float*)d_in[13];
  const float* ln2_w    = (const float*)d_in[14];
  const float* wg       = (const float*)d_in[15];
  const float* wu       = (const float*)d_in[16];
  const float* wo       = (const float*)d_in[17];
  const float* ln_out_w = (const float*)d_in[18];
  float* out = (float*)d_out;

  char* ws = (char*)d_ws;
  const size_t KB = 1024, MB = 1u << 20;
  float* h       = (float*)(ws + 0);
  u16*   h1      = (u16*)  (ws + 4*MB);
  u16*   h2      = (u16*)  (ws + 6*MB);
  u16*   qkvb    = (u16*)  (ws + 8*MB);
  u16*   qvT     = (u16*)  (ws + 12*MB);
  u16*   keys    = (u16*)  (ws + 14*MB);
  u16*   valT    = (u16*)  (ws + 16*MB);
  u16*   queries = (u16*)  (ws + 18*MB);
  float* beta    = (float*)(ws + 20*MB);
  u16*   attn    = (u16*)  (ws + 20*MB + 256*KB);
  u16*   delt    = (u16*)  (ws + 22*MB + 256*KB);
  float* lo0     = (float*)(ws + 24*MB + 256*KB);
  float* lo1     = (float*)(ws + 28*MB + 256*KB);
  float* gl0     = (float*)(ws + 32*MB + 256*KB);
  float* gl1     = (float*)(ws + 36*MB + 256*KB);
  float* gbuf    = (float*)(ws + 40*MB + 256*KB);
  u16*   mcomb   = (u16*)  (ws + 44*MB + 256*KB);
  u16*   hn      = (u16*)  (ws + 46*MB + 256*KB);
  u16*   g16     = (u16*)  (ws + 4*MB);
  u16*   u16b    = (u16*)  (ws + 12*MB);
  u16*   sbuf    = (u16*)  (ws + 20*MB);

  // bf16 weight region
  u16* wb = (u16*)(ws + 48*MB + 512*KB);
  size_t off = 0; auto nx = [&](size_t n){ size_t o = off; off += n; return o; };
  const size_t nEmb = 32768000ULL, nQkv = 12582912ULL, nSq = 4194304ULL, nFf = 16777216ULL;
  u16* wemb  = wb + nx(nEmb);
  u16* wqkv  = wb + nx(nQkv);
  u16* wswa  = wb + nx(nSq);
  u16* wk    = wb + nx(nSq);
  u16* wv    = wb + nx(nSq);
  u16* wq    = wb + nx(nSq);
  u16* wmem  = wb + nx(nSq);
  u16* wgate = wb + nx(nSq);
  u16* wcomb = wb + nx(nSq);
  u16* wwg   = wb + nx(nFf);
  u16* wwu   = wb + nx(nFf);
  u16* wwo   = wb + nx(nFf);
  const size_t NEED = 48*MB + 512*KB + off * 2;
  const bool bw = (ws_size >= NEED);

  auto MG = [&](int nblk, GBatch& gbv){
    if (bw) flm_mgemm<true><<<nblk, 512, 0, stream>>>(gbv);
    else    flm_mgemm<false><<<nblk, 512, 0, stream>>>(gbv);
  };

  if (bw){
    CBatch cb;
    const float* srcs[12] = {embed, qkv_w, swa_out_w, k_w, v_w, q_w,
                             mem_out_w, gate_w, comb_w, wg, wu, wo};
    const size_t ns[12] = {nEmb, nQkv, nSq, nSq, nSq, nSq, nSq, nSq, nSq, nFf, nFf, nFf};
    long long acc4 = 0;
    for (int i = 0; i < 12; i++){ cb.s[i] = srcs[i]; cb.p4[i] = acc4; acc4 += (long long)(ns[i] >> 2); }
    cb.p4[12] = acc4; cb.dst = wb;
    flm_conv<<<dim3(1024, 12), 256, 0, stream>>>(cb);
  }

  flm_embed<<<1024, 256, 0, stream>>>(x, embed, ln_in_w, h);

  for (int l = 0; l < 4; l++){
    const size_t lq = (size_t)l * 3145728, ls = (size_t)l * 1048576, lf = (size_t)l * 4194304;
    const float* Wqkv  = bw ? (const float*)(wqkv  + lq) : qkv_w     + lq;
    const float* WqkvV = bw ? (const float*)(wqkv  + lq + 2048*1024ULL) : qkv_w + lq + 2048*1024ULL;
    const float* Wk    = bw ? (const float*)(wk    + ls) : k_w       + ls;
    const float* Wv    = bw ? (const float*)(wv    + ls) : v_w       + ls;
    const float* Wq    = bw ? (const float*)(wq    + ls) : q_w       + ls;
    const float* Wswa  = bw ? (const float*)(wswa  + ls) : swa_out_w + ls;
    const float* Wmem  = bw ? (const float*)(wmem  + ls) : mem_out_w + ls;
    const float* Wgate = bw ? (const float*)(wgate + ls) : gate_w    + ls;
    const float* Wcomb = bw ? (const float*)(wcomb + ls) : comb_w    + ls;
    const float* Wwg   = bw ? (const float*)(wwg   + lf) : wg        + lf;
    const float* Wwu   = bw ? (const float*)(wwu   + lf) : wu        + lf;
    const float* Wwo   = bw ? (const float*)(wwo   + lf) : wo        + lf;

    flm_rms<<<1024, 256, 0, stream>>>(h, ln1_w + l*1024, lnd_w + l*1024, h1, h2);

    // batch1: qk(128) + qvT(64,T) + k(64) + valT(64,T) + q(64) + gate(64) = 448, all K=1024
    {
      GBatch gb;
      gb.d[0] = mkd(h1, 1024, Wqkv,  1024, nullptr, qkvb,    2048, 0, 1024, 0,   1);
      gb.d[1] = mkd(h1, 1024, WqkvV, 1024, nullptr, qvT,     1024, 0, 1024, 128, 2);
      gb.d[2] = mkd(h2, 1024, Wk,    1024, nullptr, keys,    1024, 0, 1024, 192, 1);
      gb.d[3] = mkd(h2, 1024, Wv,    1024, nullptr, valT,    1024, 0, 1024, 256, 2);
      gb.d[4] = mkd(h2, 1024, Wq,    1024, nullptr, queries, 1024, 0, 1024, 320, 1);
      gb.d[5] = mkd(h1, 1024, Wgate, 1024, gbuf,    nullptr, 1024, 0, 1024, 384, 0);
      gb.ng = 6; gb.total = 448;
      MG(448, gb);
    }
    flm_betanorm<<<1024, 256, 0, stream>>>(h2, beta_w + (size_t)l*16*1024, beta, keys, queries);
    flm_attn<<<dim3(16, 16, 2), 256, 0, stream>>>(qkvb, qvT, keys, valT, queries, beta, attn, delt);

    if (bw){
      // batch2: {swa,mem} x {K half} = 4 x 64 = 256 blocks, all K=512, plain stores
      GBatch gb;
      gb.d[0] = mkd(attn, 1024, Wswa, 1024, lo0, nullptr, 1024, 0,   512,  0,   0);
      gb.d[1] = mkd(attn, 1024, Wswa, 1024, lo1, nullptr, 1024, 512, 1024, 64,  0);
      gb.d[2] = mkd(delt, 1024, Wmem, 1024, gl0, nullptr, 1024, 0,   512,  128, 0);
      gb.d[3] = mkd(delt, 1024, Wmem, 1024, gl1, nullptr, 1024, 512, 1024, 192, 0);
      gb.d[4] = gb.d[3]; gb.d[4].blk0 = 0x7fffffff;
      gb.d[5] = gb.d[4];
      gb.ng = 4; gb.total = 256;
      MG(256, gb);
      flm_mix5<<<1024, 256, 0, stream>>>(gbuf, lo0, lo1, gl0, gl1, mcomb);
    } else {
      GBatch gb;
      gb.d[0] = mkd(attn, 1024, Wswa, 1024, lo0, nullptr, 1024, 0, 1024, 0, 0);
      gb.d[1] = mkd(delt, 1024, Wmem, 1024, gl0, nullptr, 1024, 0, 1024, 64, 0);
      gb.d[2] = gb.d[1]; gb.d[2].blk0 = 0x7fffffff;
      gb.d[3] = gb.d[2]; gb.d[4] = gb.d[2]; gb.d[5] = gb.d[2];
      gb.ng = 2; gb.total = 128;
      MG(128, gb);
      flm_mix<<<1024, 256, 0, stream>>>(gbuf, lo0, gl0, mcomb);
    }

    // comb: split-K x2 (homogeneous K=512), atomicAdd into live f32 h
    {
      GBatch gb;
      gb.d[0] = mkd(mcomb, 1024, Wcomb, 1024, h, nullptr, 1024, 0, 512, 0, 5);
      gb.d[1] = mkd(mcomb, 1024, Wcomb, 1024, h, nullptr, 1024, 512, 1024, 64, 5);
      gb.d[2] = gb.d[1]; gb.d[2].blk0 = 0x7fffffff;
      gb.d[3] = gb.d[2]; gb.d[4] = gb.d[2]; gb.d[5] = gb.d[2];
      gb.ng = 2; gb.total = 128;
      MG(128, gb);
    }
    flm_rms<<<1024, 256, 0, stream>>>(h, ln2_w + l*1024, nullptr, hn, nullptr);
    // batch3: wg -> g16 (256) + wu -> u16b (256) = 512, bf16 stores
    {
      GBatch gb;
      gb.d[0] = mkd(hn, 1024, Wwg, 1024, nullptr, g16, 4096, 0, 1024, 0, 1);
      gb.d[1] = mkd(hn, 1024, Wwu, 1024, nullptr, u16b, 4096, 0, 1024, 256, 1);
      gb.d[2] = gb.d[1]; gb.d[2].blk0 = 0x7fffffff;
      gb.d[3] = gb.d[2]; gb.d[4] = gb.d[2]; gb.d[5] = gb.d[2];
      gb.ng = 2; gb.total = 512;
      MG(512, gb);
    }
    flm_silu<<<4096, 256, 0, stream>>>(g16, u16b, sbuf);
    // wo: split-K x4, atomicAdd into h
    {
      GBatch gb;
      for (int s = 0; s < 4; s++)
        gb.d[s] = mkd(sbuf, 4096, Wwo, 4096, h, nullptr, 1024, s*1024, (s+1)*1024, s*64, 5);
      gb.d[4] = gb.d[3]; gb.d[4].blk0 = 0x7fffffff;
      gb.d[5] = gb.d[4];
      gb.ng = 4; gb.total = 256;
      MG(256, gb);
    }
  }

  flm_rms<<<1024, 256, 0, stream>>>(h, ln_out_w, nullptr, hn, nullptr);
  // head: 250 col-tiles x 8 row-tiles = 2000 blocks
  {
    GBatch gb;
    gb.d[0] = mkd(hn, 1024, bw ? (const float*)wemb : embed, 1024, out, nullptr, 32000,
                  0, 1024, 0, 0);
    gb.d[1] = gb.d[0]; gb.d[1].blk0 = 0x7fffffff;
    gb.d[2] = gb.d[1]; gb.d[3] = gb.d[1]; gb.d[4] = gb.d[1]; gb.d[5] = gb.d[1];
    gb.ng = 1; gb.total = 2000;
    MG(2000, gb);
  }
}